// Round 1
// baseline (207.390 us; speedup 1.0000x reference)
//
#include <hip/hip_runtime.h>

// OrthogonalLinear: pyramid Givens circuit, n = m = 512, B = 256.
// T = 1021 brickwork layers; layer t has gates (i, i+1) for
// i = (t&1), (t&1)+2, ..., min(t, 1020-t).
// theta index of gate (t, i): k = (t+i)/2 + 1, idx = k(k-1)/2 + (k-1-i).

#define T_LAYERS 1021
#define SLOTS    256      // padded (c,s) slots per layer: 64 lanes * 4 gates
#define N_WIRES  512
#define BATCH    256

// ---------------- kernel 1: padded cos/sin tables ----------------
__global__ __launch_bounds__(256) void sincos_kernel(
    const float* __restrict__ thetas,
    float* __restrict__ C, float* __restrict__ S) {
  int idx = blockIdx.x * blockDim.x + threadIdx.x;
  if (idx >= T_LAYERS * SLOTS) return;
  int t = idx >> 8;          // layer
  int e = idx & 255;         // slot within layer
  int L = e >> 2;            // lane
  int j = e & 3;             // gate slot within lane
  int i = 8 * L + 2 * j + (t & 1);   // wire index of gate (i, i+1)
  float c = 1.0f, s = 0.0f;
  int imax = min(t, 1020 - t);
  if (i <= imax) {
    int k = ((t + i) >> 1) + 1;
    int tidx = (k * (k - 1)) / 2 + (k - 1 - i);
    float th = thetas[tidx];
    sincosf(th, &s, &c);
  }
  C[idx] = c;
  S[idx] = s;
}

// ---------------- kernel 2: apply circuit, wave per row ----------------
__device__ __forceinline__ void gate(float& a, float& b, float c, float s) {
  float na = fmaf(c, a, s * b);
  float nb = fmaf(c, b, -(s * a));
  a = na;
  b = nb;
}

struct CS { float4 cE, sE, cO, sO; };  // one even+odd layer pair

__device__ __forceinline__ void even_layer(float (&v)[8], float4 c, float4 s) {
  gate(v[0], v[1], c.x, s.x);
  gate(v[2], v[3], c.y, s.y);
  gate(v[4], v[5], c.z, s.z);
  gate(v[6], v[7], c.w, s.w);
}

__device__ __forceinline__ void odd_layer(float (&v)[8], float4 c, float4 s,
                                          int lane) {
  // gates at i = 8L+1, 8L+3, 8L+5 internal; i = 8L+7 spans to lane L+1's v0;
  // our v0 is updated by lane L-1's slot-3 gate (i = 8L-1).
  float rv0 = __shfl_down(v[0], 1);   // right neighbor's wire 8L+8 (pre-update)
  float lv7 = __shfl_up(v[7], 1);     // left neighbor's wire 8L-1 (pre-update)
  float cl  = __shfl_up(c.w, 1);      // left neighbor's boundary gate c
  float sl  = __shfl_up(s.w, 1);      // left neighbor's boundary gate s
  cl = (lane == 0) ? 1.0f : cl;       // no gate below wire 0
  sl = (lane == 0) ? 0.0f : sl;
  gate(v[1], v[2], c.x, s.x);
  gate(v[3], v[4], c.y, s.y);
  gate(v[5], v[6], c.z, s.z);
  float nv7 = fmaf(c.w, v[7], s.w * rv0);     // a-side of gate (8L+7, 8L+8)
  float nv0 = fmaf(cl, v[0], -(sl * lv7));    // b-side of gate (8L-1, 8L)
  v[7] = nv7;
  v[0] = nv0;
}

__device__ __forceinline__ CS load_pair(const float* Cb, const float* Sb, int p) {
  CS r;
  r.cE = *(const float4*)(Cb + (2 * p) * SLOTS);
  r.sE = *(const float4*)(Sb + (2 * p) * SLOTS);
  r.cO = *(const float4*)(Cb + (2 * p + 1) * SLOTS);
  r.sO = *(const float4*)(Sb + (2 * p + 1) * SLOTS);
  return r;
}

__global__ __launch_bounds__(64) void circuit_kernel(
    const float* __restrict__ x, const float* __restrict__ C,
    const float* __restrict__ S, const float* __restrict__ bias,
    float* __restrict__ out) {
  const int row = blockIdx.x;
  const int lane = threadIdx.x;

  const float* xr = x + row * N_WIRES + lane * 8;
  float4 x0 = *(const float4*)(xr);
  float4 x1 = *(const float4*)(xr + 4);
  float v[8] = {x0.x, x0.y, x0.z, x0.w, x1.x, x1.y, x1.z, x1.w};

  const float* Cb = C + lane * 4;
  const float* Sb = S + lane * 4;

  // 510 even/odd layer pairs (t = 0..1019), then final even layer t = 1020.
  // 3-slot ring: prefetch distance ~2 pairs to cover L2 latency (1 wave/SIMD,
  // no TLP to hide it otherwise).
  CS R0 = load_pair(Cb, Sb, 0);
  CS R1 = load_pair(Cb, Sb, 1);
  CS R2 = load_pair(Cb, Sb, 2);

  int u = 0;
  for (; u + 5 < 510; u += 3) {   // u = 0,3,...,504 -> ends at u = 507
    even_layer(v, R0.cE, R0.sE);
    odd_layer(v, R0.cO, R0.sO, lane);
    R0 = load_pair(Cb, Sb, u + 3);
    even_layer(v, R1.cE, R1.sE);
    odd_layer(v, R1.cO, R1.sO, lane);
    R1 = load_pair(Cb, Sb, u + 4);
    even_layer(v, R2.cE, R2.sE);
    odd_layer(v, R2.cO, R2.sO, lane);
    R2 = load_pair(Cb, Sb, u + 5);
  }
  // pairs 507, 508, 509
  even_layer(v, R0.cE, R0.sE);
  odd_layer(v, R0.cO, R0.sO, lane);
  even_layer(v, R1.cE, R1.sE);
  odd_layer(v, R1.cO, R1.sO, lane);
  even_layer(v, R2.cE, R2.sE);
  odd_layer(v, R2.cO, R2.sO, lane);
  // final even layer t = 1020
  float4 cF = *(const float4*)(Cb + 1020 * SLOTS);
  float4 sF = *(const float4*)(Sb + 1020 * SLOTS);
  even_layer(v, cF, sF);

  const float* br = bias + lane * 8;
  float4 b0 = *(const float4*)(br);
  float4 b1 = *(const float4*)(br + 4);
  float4 o0 = {v[0] + b0.x, v[1] + b0.y, v[2] + b0.z, v[3] + b0.w};
  float4 o1 = {v[4] + b1.x, v[5] + b1.y, v[6] + b1.z, v[7] + b1.w};
  float* orow = out + row * N_WIRES + lane * 8;
  *(float4*)(orow) = o0;
  *(float4*)(orow + 4) = o1;
}

extern "C" void kernel_launch(void* const* d_in, const int* in_sizes, int n_in,
                              void* d_out, int out_size, void* d_ws,
                              size_t ws_size, hipStream_t stream) {
  const float* x = (const float*)d_in[0];       // (256, 512) f32
  const float* thetas = (const float*)d_in[1];  // (130816,) f32
  const float* bias = (const float*)d_in[2];    // (512,) f32
  float* out = (float*)d_out;                   // (256, 512) f32

  float* C = (float*)d_ws;                      // 1021*256 floats
  float* S = C + T_LAYERS * SLOTS;              // 1021*256 floats (~2.1 MB total)

  sincos_kernel<<<(T_LAYERS * SLOTS + 255) / 256, 256, 0, stream>>>(thetas, C, S);
  circuit_kernel<<<BATCH, 64, 0, stream>>>(x, C, S, bias, out);
}

// Round 2
// 133.934 us; speedup vs baseline: 1.5484x; 1.5484x over previous
//
#include <hip/hip_runtime.h>

// OrthogonalLinear: pyramid Givens circuit, n = m = 512, B = 256.
// T = 1021 brickwork layers; layer t has gates (i, i+1) for
// i = (t&1), (t&1)+2, ..., min(t, 1020-t).
// theta index of gate (t, i): k = (t+i)/2 + 1, idx = k(k-1)/2 + (k-1-i).
//
// Table layout (d_ws): 510 pair-blocks of 1024 floats. Pair p covers layers
// t=2p (even) and t=2p+1 (odd). Within a block, lane L owns 16 contiguous
// floats at [L*16, L*16+16): [cE0..3 | sE0..3 | cO0..3 | sO0..3] -> one lane
// reads 64 contiguous bytes = 4 x dwordx4 at imm offsets 0/16/32/48.
// Final layer t=1020 stored after the pairs: lane L at [FINAL_OFF + L*8, +8):
// [c0..3 | s0..3]. Total = 510*1024 + 512 = 522752 floats (same ws as R1).

#define N_WIRES 512
#define BATCH   256
#define PAIRS   510
#define PAIR_FLOATS 1024
#define FINAL_OFF (PAIRS * PAIR_FLOATS)
#define PF 10              // prefetch ring depth (pairs); 510 % 10 == 0

// ---------------- kernel 1: padded cos/sin tables ----------------
__global__ __launch_bounds__(256) void sincos_kernel(
    const float* __restrict__ thetas, float* __restrict__ W) {
  int tid = blockIdx.x * blockDim.x + threadIdx.x;
  const int NPAIR = PAIRS * 512;   // 261120 (p, h, L, j) slots
  if (tid < NPAIR) {
    int p = tid >> 9;
    int r = tid & 511;
    int L = r >> 3;
    int h = (r >> 2) & 1;
    int j = r & 3;
    int t = 2 * p + h;
    int i = 8 * L + 2 * j + h;
    float c = 1.0f, s = 0.0f;
    int imax = min(t, 1020 - t);
    if (i <= imax) {
      int k = ((t + i) >> 1) + 1;
      int tidx = (k * (k - 1)) / 2 + (k - 1 - i);
      __sincosf(thetas[tidx], &s, &c);
    }
    int base = p * PAIR_FLOATS + L * 16 + h * 8 + j;
    W[base] = c;
    W[base + 4] = s;
  } else if (tid < NPAIR + 256) {
    // final even layer t = 1020: only gate i = 0 is live (imax = 0)
    int e = tid - NPAIR;
    int L = e >> 2, j = e & 3;
    int i = 8 * L + 2 * j;
    float c = 1.0f, s = 0.0f;
    if (i == 0) {
      // k = 511, tidx = 511*510/2 + 510 = 130815 (last theta)
      __sincosf(thetas[130815], &s, &c);
    }
    int base = FINAL_OFF + L * 8 + j;
    W[base] = c;
    W[base + 4] = s;
  }
}

// ---------------- kernel 2: apply circuit, wave per row ----------------
__device__ __forceinline__ void gate(float& a, float& b, float c, float s) {
  float na = fmaf(c, a, s * b);
  float nb = fmaf(c, b, -(s * a));
  a = na;
  b = nb;
}

struct CS { float4 cE, sE, cO, sO; };

__device__ __forceinline__ CS load_pair(const float* __restrict__ Wl, int p) {
  const float4* q = (const float4*)(Wl + p * PAIR_FLOATS);
  CS r;
  r.cE = q[0];
  r.sE = q[1];
  r.cO = q[2];
  r.sO = q[3];
  return r;
}

__device__ __forceinline__ void even_layer(float (&v)[8], float4 c, float4 s) {
  gate(v[0], v[1], c.x, s.x);
  gate(v[2], v[3], c.y, s.y);
  gate(v[4], v[5], c.z, s.z);
  gate(v[6], v[7], c.w, s.w);
}

__device__ __forceinline__ void odd_layer(float (&v)[8], float4 c, float4 s,
                                          int lane) {
  // gates at i = 8L+1, 8L+3, 8L+5 internal; i = 8L+7 spans to lane L+1's v0;
  // our v0 is updated by lane L-1's slot-3 gate (i = 8L-1).
  float rv0 = __shfl_down(v[0], 1);   // right neighbor's wire 8L+8 (pre-update)
  float lv7 = __shfl_up(v[7], 1);     // left neighbor's wire 8L-1 (pre-update)
  float cl  = __shfl_up(c.w, 1);      // left neighbor's boundary gate c
  float sl  = __shfl_up(s.w, 1);      // left neighbor's boundary gate s
  cl = (lane == 0) ? 1.0f : cl;       // no gate below wire 0
  sl = (lane == 0) ? 0.0f : sl;
  gate(v[1], v[2], c.x, s.x);
  gate(v[3], v[4], c.y, s.y);
  gate(v[5], v[6], c.z, s.z);
  float nv7 = fmaf(c.w, v[7], s.w * rv0);     // a-side of gate (8L+7, 8L+8)
  float nv0 = fmaf(cl, v[0], -(sl * lv7));    // b-side of gate (8L-1, 8L)
  v[7] = nv7;
  v[0] = nv0;
}

__global__ __launch_bounds__(64, 1) void circuit_kernel(
    const float* __restrict__ x, const float* __restrict__ W,
    const float* __restrict__ bias, float* __restrict__ out) {
  const int row = blockIdx.x;
  const int lane = threadIdx.x;

  const float* xr = x + row * N_WIRES + lane * 8;
  float4 x0 = *(const float4*)(xr);
  float4 x1 = *(const float4*)(xr + 4);
  float v[8] = {x0.x, x0.y, x0.z, x0.w, x1.x, x1.y, x1.z, x1.w};

  const float* Wl = W + lane * 16;   // this lane's 64B record within a pair

  // Deep prefetch ring: PF pairs (~PF*100 cycles of compute in flight) to
  // cover L3/cross-XCD latency (~600-900 cyc). Fully unrolled -> R[] stays
  // in registers (160 VGPRs for the ring at PF=10).
  CS R[PF];
#pragma unroll
  for (int s = 0; s < PF; ++s) R[s] = load_pair(Wl, s);

  for (int blk = 0; blk < (PAIRS / PF) - 1; ++blk) {   // 50 iterations
    const int base = blk * PF + PF;
#pragma unroll
    for (int s = 0; s < PF; ++s) {
      even_layer(v, R[s].cE, R[s].sE);
      odd_layer(v, R[s].cO, R[s].sO, lane);
      R[s] = load_pair(Wl, base + s);
    }
  }

  // prefetch final layer before the drain
  const float* F = W + FINAL_OFF + lane * 8;
  float4 cF = *(const float4*)(F);
  float4 sF = *(const float4*)(F + 4);

#pragma unroll
  for (int s = 0; s < PF; ++s) {     // drain: pairs 500..509
    even_layer(v, R[s].cE, R[s].sE);
    odd_layer(v, R[s].cO, R[s].sO, lane);
  }

  even_layer(v, cF, sF);             // final even layer t = 1020

  const float* br = bias + lane * 8;
  float4 b0 = *(const float4*)(br);
  float4 b1 = *(const float4*)(br + 4);
  float4 o0 = {v[0] + b0.x, v[1] + b0.y, v[2] + b0.z, v[3] + b0.w};
  float4 o1 = {v[4] + b1.x, v[5] + b1.y, v[6] + b1.z, v[7] + b1.w};
  float* orow = out + row * N_WIRES + lane * 8;
  *(float4*)(orow) = o0;
  *(float4*)(orow + 4) = o1;
}

extern "C" void kernel_launch(void* const* d_in, const int* in_sizes, int n_in,
                              void* d_out, int out_size, void* d_ws,
                              size_t ws_size, hipStream_t stream) {
  const float* x = (const float*)d_in[0];       // (256, 512) f32
  const float* thetas = (const float*)d_in[1];  // (130816,) f32
  const float* bias = (const float*)d_in[2];    // (512,) f32
  float* out = (float*)d_out;                   // (256, 512) f32

  float* W = (float*)d_ws;  // 522752 floats = ~2.09 MB

  const int nslots = PAIRS * 512 + 256;
  sincos_kernel<<<(nslots + 255) / 256, 256, 0, stream>>>(thetas, W);
  circuit_kernel<<<BATCH, 64, 0, stream>>>(x, W, bias, out);
}